// Round 1
// 335.895 us; speedup vs baseline: 1.0280x; 1.0280x over previous
//
#include <hip/hip_runtime.h>

typedef __bf16 bf16_t;
typedef __bf16 bf16x8 __attribute__((ext_vector_type(8)));
typedef __bf16 bf16x4 __attribute__((ext_vector_type(4)));
typedef float  f32x4  __attribute__((ext_vector_type(4)));

#define NB 16   // B
#define NN 30   // N
#define NT 50   // T
#define ND 4    // D
#define NK 4    // K experts
#define NE 870  // E = N*(N-1)

// canonical workspace layout (element offsets from ws+16, all %8==0 -> 16B aligned)
#define C_INPUTS   0        // 96000
#define C_RELTYPE  96000    // 55680  rel_type TRANSPOSED to [b][k][e] (v4)
#define C_B2       152192   // 512
#define C_OB1      152704   // 128
#define C_OB2      152832   // 128
#define C_OW3      152960   // 512
#define C_OB3      153472   // 4 (pad to 8)
#define C_W1F      153480   // 16384  W1 frags [k][ct][quad][lm][j]; b1 folded at quad1,j0
#define C_W2F      169864   // 65536  W2 frags [k][kc][ct][quad*16+lm][j]
#define C_OW1F     235400   // 20480  oW1 frags [ct][kc(5)][quad][lm][j] (kk>=132 zero)
#define C_OW2F     255880   // 16384  oW2 frags [ct][kc(4)][quad][lm][j]
#define AGG_BYTE_OFF (1u << 20)   // aggbuf (fp32) at ws + 1MB

union U4 { unsigned w[4]; bf16x8 v; };
union U2 { unsigned w[2]; bf16x4 v; };

__device__ __forceinline__ bf16x8 bzero8() {
  bf16x8 z;
#pragma unroll
  for (int j = 0; j < 8; ++j) z[j] = (bf16_t)0.0f;
  return z;
}

__device__ __forceinline__ f32x4 make4(float a, float b, float c, float d) {
  f32x4 v; v[0] = a; v[1] = b; v[2] = c; v[3] = d; return v;
}

// relu + cvt to bf16 + packed 8B store (node kernel)
__device__ __forceinline__ void pack_store4(bf16_t* dst, f32x4 a) {
  bf16x4 v;
  v[0] = (bf16_t)fmaxf(a[0], 0.0f);
  v[1] = (bf16_t)fmaxf(a[1], 0.0f);
  v[2] = (bf16_t)fmaxf(a[2], 0.0f);
  v[3] = (bf16_t)fmaxf(a[3], 0.0f);
  *(bf16x4*)dst = v;
}

// Quad-transpose building block (v4): given per-lane words X,Y (X from ct=2kc,
// Y from ct=2kc+1; word w packs {r=2w, r=2w+1}), produce
//   zlo@quad = (quad<2 ? X : Y) @ lane(((2*quad)&3)*16+lm)     -> af word w
//   zhi@quad = (quad<2 ? X : Y) @ lane(((2*quad+1)&3)*16+lm)   -> af word w+2
// permlane32_swap(X,Y) = {[X0,X1,Y0,Y1],[X2,X3,Y2,Y3]} (rows of 16 lanes);
// permlane16_swap of those = {[X0,X2,Y0,Y2],[X1,X3,Y1,Y3]} = {zlo, zhi}.
__device__ __forceinline__ void qswap(unsigned x, unsigned y,
                                      unsigned& zlo, unsigned& zhi) {
#if __has_builtin(__builtin_amdgcn_permlane32_swap) && __has_builtin(__builtin_amdgcn_permlane16_swap)
  auto t = __builtin_amdgcn_permlane32_swap(x, y, false, false);
  auto z = __builtin_amdgcn_permlane16_swap(t[0], t[1], false, false);
  zlo = z[0]; zhi = z[1];
#else
  const int lane = threadIdx.x & 63;
  const int quad = lane >> 4;
  const int lm   = lane & 15;
  const int s0 = (((2 * quad) & 3) << 4) + lm;
  const int s1 = (((2 * quad + 1) & 3) << 4) + lm;
  const unsigned a0 = (unsigned)__shfl((int)x, s0, 64);
  const unsigned b0 = (unsigned)__shfl((int)y, s0, 64);
  const unsigned a1 = (unsigned)__shfl((int)x, s1, 64);
  const unsigned b1 = (unsigned)__shfl((int)y, s1, 64);
  zlo = (quad < 2) ? a0 : b0;
  zhi = (quad < 2) ? a1 : b1;
#endif
}

// ---------------------------------------------------------------------------
// dtype detection + canonicalization (bf16) + weight fragment pre-permutation
// ---------------------------------------------------------------------------
__device__ __forceinline__ int detect_isbf16(const void* p) {
  const unsigned short* w = (const unsigned short*)p;
  int c = 0;
#pragma unroll 4
  for (int i = 0; i < 256; i += 2) {
    const int e = (w[i] >> 7) & 0xFF;
    if (e >= 100 && e <= 150) ++c;
  }
  return c >= 96;
}

__device__ __forceinline__ float ldf(const void* src, int idx, int isbf) {
  return isbf ? (float)((const bf16_t*)src)[idx] : ((const float*)src)[idx];
}

__device__ __forceinline__ void conv_arr(const void* src, bf16_t* dst, int n,
                                         int isbf, int gtid, int gsz) {
  if (isbf) {
    const unsigned short* s = (const unsigned short*)src;
    unsigned short* d = (unsigned short*)dst;
    for (int i = gtid; i < n; i += gsz) d[i] = s[i];
  } else {
    const float* s = (const float*)src;
    for (int i = gtid; i < n; i += gsz) dst[i] = (bf16_t)s[i];
  }
}

__global__ void convert_kernel(const void* inputs, const void* rel_type,
                               const void* W1, const void* b1,
                               const void* W2, const void* b2,
                               const void* oW1, const void* ob1,
                               const void* oW2, const void* ob2,
                               const void* oW3, const void* ob3,
                               void* ws)
{
  __shared__ int sflag;
  if (threadIdx.x == 0) sflag = detect_isbf16(inputs);
  __syncthreads();
  const int isbf = sflag;
  if (blockIdx.x == 0 && threadIdx.x == 0) *(int*)ws = isbf;
  bf16_t* cb = (bf16_t*)((char*)ws + 16);
  const int gtid = blockIdx.x * blockDim.x + threadIdx.x;
  const int gsz  = gridDim.x * blockDim.x;

  conv_arr(inputs,   cb + C_INPUTS,  96000, isbf, gtid, gsz);
  // rel_type transposed to [b][k][e] so the edge kernel's per-k scatter loads
  // are contiguous in e (coalesced).
  for (int i = gtid; i < 55680; i += gsz) {
    const int bq  = i / (NK * NE);
    const int rem = i - bq * (NK * NE);
    const int k   = rem / NE;
    const int e   = rem - k * NE;
    cb[C_RELTYPE + i] = (bf16_t)ldf(rel_type, (bq * NE + e) * NK + k, isbf);
  }
  conv_arr(b2,  cb + C_B2,  512, isbf, gtid, gsz);
  conv_arr(ob1, cb + C_OB1, 128, isbf, gtid, gsz);
  conv_arr(ob2, cb + C_OB2, 128, isbf, gtid, gsz);
  conv_arr(oW3, cb + C_OW3, 512, isbf, gtid, gsz);
  conv_arr(ob3, cb + C_OB3, 4,   isbf, gtid, gsz);

  // W1 fragments: idx = (((k*8+ct)*4+quad)*16+lm)*8+j
  for (int i = gtid; i < 16384; i += gsz) {
    const int j = i & 7, lm = (i >> 3) & 15, quad = (i >> 7) & 3;
    const int ct = (i >> 9) & 7, k = (i >> 12) & 3;
    float v = 0.0f;
    if (quad == 0)                 v = ldf(W1, k * 1024 + j * 128 + ct * 16 + lm, isbf);
    else if (quad == 1 && j == 0)  v = ldf(b1, k * 128 + ct * 16 + lm, isbf);
    cb[C_W1F + i] = (bf16_t)v;
  }
  // W2 fragments: idx = (((k*4+kc)*8+ct)*64 + quad*16+lm)*8 + j
  for (int i = gtid; i < 65536; i += gsz) {
    const int j = i & 7;
    const int l64 = (i >> 3) & 63;
    const int ct = (i >> 9) & 7, kc = (i >> 12) & 3, k = (i >> 14) & 3;
    const int quad = l64 >> 4, lm = l64 & 15;
    const int kk = kc * 32 + quad * 8 + j;
    cb[C_W2F + i] = (bf16_t)ldf(W2, k * 16384 + kk * 128 + ct * 16 + lm, isbf);
  }
  // oW1 fragments
  for (int i = gtid; i < 20480; i += gsz) {
    const int j = i & 7, lm = (i >> 3) & 15, quad = (i >> 7) & 3;
    const int rem = i >> 9;
    const int kc = rem % 5, ct = rem / 5;
    const int kk = kc * 32 + quad * 8 + j;
    float v = 0.0f;
    if (kk < 132) v = ldf(oW1, kk * 128 + ct * 16 + lm, isbf);
    cb[C_OW1F + i] = (bf16_t)v;
  }
  // oW2 fragments
  for (int i = gtid; i < 16384; i += gsz) {
    const int j = i & 7, lm = (i >> 3) & 15, quad = (i >> 7) & 3;
    const int kc = (i >> 9) & 3, ct = (i >> 11) & 7;
    const int kk = kc * 32 + quad * 8 + j;
    cb[C_OW2F + i] = (bf16_t)ldf(oW2, kk * 128 + ct * 16 + lm, isbf);
  }
}

// ---------------------------------------------------------------------------
// Edge kernel v4: barrier-free main loop. Each wave owns one strip (16 edges)
// per tile and ALL 128 output columns; the layer1->layer2 fragment transpose
// (cross-quad only, lm-preserving) is done in registers via
// permlane32_swap+permlane16_swap, so the h tile never touches LDS.
// sfrag (S A-frags) is wave-private (strip g has g%4 == wave) -> scatter and
// read without any barrier. Barriers: 1 after xl staging + 3 in the finalize.
// VGPRs: w2r 128 + w1r 32 + aggacc 32 + b2s 8 + misc ~= 250 -> (256,2).
// ---------------------------------------------------------------------------
struct EdgeSmem {
  union { bf16_t sfrag[7168]; float aggf[2048]; } u;   // 14336 B
  bf16_t xl[128];                                      // 256 B (120..127 zero)
};                                                      // 14592 B

__global__ __launch_bounds__(256, 2)
void edge_kernel(const bf16_t* __restrict__ inputs,
                 const bf16_t* __restrict__ rtT,     // [b][k][e]
                 const bf16_t* __restrict__ w1f_g,
                 const bf16_t* __restrict__ w2f_g,
                 const bf16_t* __restrict__ b2c,
                 float* __restrict__ aggbuf)
{
  __shared__ EdgeSmem s;
  const int tid   = threadIdx.x;
  const int bid   = blockIdx.x;
  const int nhalf = bid & 1;
  const int bt    = bid >> 1;
  const int b     = bt / NT;
  const int t     = bt - b * NT;
  const int wave  = tid >> 6;
  const int lane  = tid & 63;
  const int quad  = lane >> 4;
  const int lm    = lane & 15;

  // ---- one-time staging ----
  if (tid < 30)
    *(uint2*)&s.xl[tid * 4] = *(const uint2*)&inputs[((b * NN + tid) * NT + t) * ND];
  if (tid < 8) s.xl[120 + tid] = (bf16_t)0.0f;   // pad nodes (recv==30 for e>=435)

  // zero my wave's sfrag strips (wave-private: strip g iff g%4==wave)
  {
    bf16x4 z; z[0] = z[1] = z[2] = z[3] = (bf16_t)0.0f;
#pragma unroll
    for (int s7 = 0; s7 < 7; ++s7)
      *(bf16x4*)&s.u.sfrag[((s7 * 4 + wave) * 64 + lane) * 4] = z;
  }
  __syncthreads();   // xl visible to all waves

  f32x4 aggacc[8];
#pragma unroll
  for (int ct = 0; ct < 8; ++ct) aggacc[ct] = make4(0.f, 0.f, 0.f, 0.f);

#pragma unroll 1
  for (int k = 0; k < NK; ++k) {
    // ---- per-k weight hoist (L2-hot, 168 VGPRs) ----
    bf16x8 w1r[8];
    bf16x8 w2r[8][4];
    float  b2s[8];
#pragma unroll
    for (int ct = 0; ct < 8; ++ct) {
      w1r[ct] = *(const bf16x8*)&w1f_g[(((k * 8 + ct) * 4 + quad) * 16 + lm) * 8];
#pragma unroll
      for (int kc = 0; kc < 4; ++kc)
        w2r[ct][kc] = *(const bf16x8*)&w2f_g[((((k * 4 + kc) * 8) + ct) * 64 + quad * 16 + lm) * 8];
      b2s[ct] = (float)b2c[k * 128 + ct * 16 + lm];
    }

    // ---- scatter S(k) for my strips only (wave-private, no barrier) ----
    {
      const bf16_t* rtk = rtT + (size_t)(b * NK + k) * NE + nhalf * 435;
#pragma unroll
      for (int it = 0; it < 2; ++it) {
        const int idx = it * 64 + lane;    // 0..127; 112 real entries
        const int s7  = idx >> 4;
        if (s7 < 7) {
          const int g = s7 * 4 + wave;
          const int i = g * 16 + (idx & 15);
          if (i < 435) {
            const int n    = i / 29;
            const int slot = (g * 64 + ((i >> 2) & 3) * 16 + n) * 4 + (i & 3);
            s.u.sfrag[slot] = rtk[i];
          }
        }
      }
    }

#pragma unroll 1
    for (int tt = 0; tt < 7; ++tt) {
      const int g = tt * 4 + wave;         // my strip this tile

      // ---- pm: layer-1 B-fragment ----
      bf16x8 pm = bzero8();
      if (quad == 0) {
        const int e    = g * 16 + lm;
        const int d29  = e / 29;
        const int recv = nhalf * 15 + d29;         // e>=435 -> 30 (zero pad)
        const int j29  = e - d29 * 29;
        const int send = j29 + (j29 >= recv);
        union { uint2 u2[2]; bf16x8 v; } c;
        c.u2[0] = *(const uint2*)&s.xl[recv * 4];
        c.u2[1] = *(const uint2*)&s.xl[send * 4];
        pm = c.v;
      } else if (quad == 1) {
        pm[0] = (bf16_t)1.0f;              // bias feature: W1F row kk=8 holds b1
      }

      // ---- layer 1 (8 MFMAs) + relu + in-register quad transpose -> af[4] ----
      // acc1[ct][r] = h[n=ct*16+quad*4+r][e=g*16+lm]; af[kc][j] must be
      // h[kc*32+quad*8+j][e=g*16+lm] -> cross-quad move, lm preserved (qswap).
      U4 af[4];
      const f32x4 z4 = make4(0.f, 0.f, 0.f, 0.f);
#pragma unroll
      for (int kc = 0; kc < 4; ++kc) {
        f32x4 aA = __builtin_amdgcn_mfma_f32_16x16x32_bf16(w1r[2 * kc],     pm, z4, 0, 0, 0);
        f32x4 aB = __builtin_amdgcn_mfma_f32_16x16x32_bf16(w1r[2 * kc + 1], pm, z4, 0, 0, 0);
        U2 pA, pB;
        pA.v[0] = (bf16_t)fmaxf(aA[0], 0.f); pA.v[1] = (bf16_t)fmaxf(aA[1], 0.f);
        pA.v[2] = (bf16_t)fmaxf(aA[2], 0.f); pA.v[3] = (bf16_t)fmaxf(aA[3], 0.f);
        pB.v[0] = (bf16_t)fmaxf(aB[0], 0.f); pB.v[1] = (bf16_t)fmaxf(aB[1], 0.f);
        pB.v[2] = (bf16_t)fmaxf(aB[2], 0.f); pB.v[3] = (bf16_t)fmaxf(aB[3], 0.f);
        qswap(pA.w[0], pB.w[0], af[kc].w[0], af[kc].w[2]);
        qswap(pA.w[1], pB.w[1], af[kc].w[1], af[kc].w[3]);
      }

      // ---- S A-fragment (wave-private sfrag, lane-linear b64 read) ----
      U4 sa;
      {
        U2 s4;
        s4.v = *(const bf16x4*)&s.u.sfrag[(g * 64 + lane) * 4];
        sa.w[0] = s4.w[0]; sa.w[1] = s4.w[1]; sa.w[2] = 0u; sa.w[3] = 0u;
      }

      // ---- layer 2 (32 MFMAs) + in-register agg (8 MFMAs) ----
#pragma unroll
      for (int ct = 0; ct < 8; ++ct) {
        f32x4 acc = make4(b2s[ct], b2s[ct], b2s[ct], b2s[ct]);
#pragma unroll
        for (int kc = 0; kc < 4; ++kc)
          acc = __builtin_amdgcn_mfma_f32_16x16x32_bf16(af[kc].v, w2r[ct][kc], acc, 0, 0, 0);
        U4 mb;
        U2 pk;
        pk.v[0] = (bf16_t)fmaxf(acc[0], 0.f); pk.v[1] = (bf16_t)fmaxf(acc[1], 0.f);
        pk.v[2] = (bf16_t)fmaxf(acc[2], 0.f); pk.v[3] = (bf16_t)fmaxf(acc[3], 0.f);
        mb.w[0] = pk.w[0]; mb.w[1] = pk.w[1]; mb.w[2] = 0u; mb.w[3] = 0u;
        aggacc[ct] = __builtin_amdgcn_mfma_f32_16x16x32_bf16(sa.v, mb.v, aggacc[ct], 0, 0, 0);
      }
    }
  }

  // ---- finalize: combine wave partials, write agg to global ----
  __syncthreads();                                   // all waves done with sfrag
  for (int i = tid; i < 2048; i += 256) s.u.aggf[i] = 0.0f;
  __syncthreads();
#pragma unroll
  for (int ct = 0; ct < 8; ++ct)
#pragma unroll
    for (int r = 0; r < 4; ++r)
      atomicAdd(&s.u.aggf[(quad * 4 + r) * 128 + ct * 16 + lm], aggacc[ct][r]);
  __syncthreads();
  for (int i = tid; i < 15 * 128; i += 256) {
    const int r = i >> 7, col = i & 127;
    aggbuf[(size_t)(bt * NN + nhalf * 15 + r) * 128 + col] = s.u.aggf[r * 128 + col];
  }
}

// ---------------------------------------------------------------------------
// Node kernel (unchanged from R10 best)
// ---------------------------------------------------------------------------
struct NodeSmem {
  bf16_t h1[64 * 136];
  bf16_t h2[64 * 136];
  bf16_t xres[64 * 4];
  float  b1f[128];
  float  b2f[128];
  float  w3f[128 * 4];
  float  b3f[4];
};

__global__ __launch_bounds__(256)
void node_kernel(const bf16_t* __restrict__ inputs,
                 const bf16_t* __restrict__ ow1f_g, const bf16_t* __restrict__ ob1,
                 const bf16_t* __restrict__ ow2f_g, const bf16_t* __restrict__ ob2,
                 const bf16_t* __restrict__ oW3, const bf16_t* __restrict__ ob3,
                 const int* __restrict__ flagptr,
                 const float* __restrict__ aggbuf,
                 void* __restrict__ outp)
{
  __shared__ NodeSmem s;
  const int tid  = threadIdx.x;
  const int wave = tid >> 6;
  const int lane = tid & 63;
  const int quad = lane >> 4;
  const int lm   = lane & 15;
  const int row  = wave * 16 + lm;
  const int r0   = blockIdx.x * 64;
  const int isbf = *flagptr;

  if (tid < 64) {
    const int r  = r0 + tid;
    const int n  = r % NN;
    const int bt = r / NN;
    const int t  = bt % NT;
    const int b  = bt / NT;
    *(uint2*)&s.xres[tid * 4] = *(const uint2*)&inputs[((b * NN + n) * NT + t) * ND];
  }
  if (tid < 128) s.b1f[tid] = (float)ob1[tid];
  else           s.b2f[tid - 128] = (float)ob2[tid - 128];
  if (tid < 4) s.b3f[tid] = (float)ob3[tid];
  for (int i = tid; i < 512; i += 256) s.w3f[i] = (float)oW3[i];
  __syncthreads();

  bf16x8 bfa[5];
  {
    const float* aggrow = aggbuf + (size_t)(r0 + row) * 128;
    float tmp[8];
    if (quad == 0) {
#pragma unroll
      for (int j = 0; j < 4; ++j) tmp[j] = (float)s.xres[row * 4 + j];
      const float4 a = *(const float4*)(aggrow);
      tmp[4] = a.x; tmp[5] = a.y; tmp[6] = a.z; tmp[7] = a.w;
    } else {
      const int c0 = quad * 8 - 4;
      const float4 a = *(const float4*)(aggrow + c0);
      const float4 d = *(const float4*)(aggrow + c0 + 4);
      tmp[0] = a.x; tmp[1] = a.y; tmp[2] = a.z; tmp[3] = a.w;
      tmp[4] = d.x; tmp[5] = d.y; tmp[6] = d.z; tmp[7] = d.w;
    }
#pragma unroll
    for (int j = 0; j < 8; ++j) bfa[0][j] = (bf16_t)tmp[j];
#pragma unroll
    for (int kc = 1; kc < 4; ++kc) {
      const int c0 = kc * 32 + quad * 8 - 4;
      const float4 a = *(const float4*)(aggrow + c0);
      const float4 d = *(const float4*)(aggrow + c0 + 4);
      tmp[0] = a.x; tmp[1] = a.y; tmp[2] = a.z; tmp[3] = a.w;
      tmp[4] = d.x; tmp[5] = d.y; tmp[6] = d.z; tmp[7] = d.w;
#pragma unroll
      for (int j = 0; j < 8; ++j) bfa[kc][j] = (bf16_t)tmp[j];
    }
    if (quad == 0) {
      const float4 a = *(const float4*)(aggrow + 124);
      tmp[0] = a.x; tmp[1] = a.y; tmp[2] = a.z; tmp[3] = a.w;
      tmp[4] = 0.f; tmp[5] = 0.f; tmp[6] = 0.f; tmp[7] = 0.f;
#pragma unroll
      for (int j = 0; j < 8; ++j) bfa[4][j] = (bf16_t)tmp[j];
    } else bfa[4] = bzero8();
  }

#pragma unroll
  for (int ct = 0; ct < 8; ++ct) {
    const int nb = ct * 16 + quad * 4;
    f32x4 acc = make4(s.b1f[nb], s.b1f[nb + 1], s.b1f[nb + 2], s.b1f[nb + 3]);
#pragma unroll
    for (int kc = 0; kc < 5; ++kc) {
      const bf16x8 w = *(const bf16x8*)&ow1f_g[(((ct * 5 + kc) * 4 + quad) * 16 + lm) * 8];
      acc = __builtin_amdgcn_mfma_f32_16x16x32_bf16(w, bfa[kc], acc, 0, 0, 0);
    }
    pack_store4(&s.h1[row * 136 + ct * 16 + quad * 4], acc);
  }

  bf16x8 af[4];
#pragma unroll
  for (int kc = 0; kc < 4; ++kc)
    af[kc] = *(const bf16x8*)&s.h1[row * 136 + kc * 32 + quad * 8];

#pragma unroll
  for (int ct = 0; ct < 8; ++ct) {
    const int mb = ct * 16 + quad * 4;
    f32x4 acc = make4(s.b2f[mb], s.b2f[mb + 1], s.b2f[mb + 2], s.b2f[mb + 3]);
#pragma unroll
    for (int kc = 0; kc < 4; ++kc) {
      const bf16x8 w = *(const bf16x8*)&ow2f_g[(((ct * 4 + kc) * 4 + quad) * 16 + lm) * 8];
      acc = __builtin_amdgcn_mfma_f32_16x16x32_bf16(w, af[kc], acc, 0, 0, 0);
    }
    pack_store4(&s.h2[row * 136 + ct * 16 + quad * 4], acc);
  }

  {
    const int rloc = tid >> 2;
    const int d    = tid & 3;
    float a3 = s.b3f[d];
#pragma unroll
    for (int g = 0; g < 16; ++g) {
      const bf16x8 hv = *(const bf16x8*)&s.h2[rloc * 136 + g * 8];
#pragma unroll
      for (int j = 0; j < 8; ++j)
        a3 += (float)hv[j] * s.w3f[(g * 8 + j) * 4 + d];
    }
    a3 += (float)s.xres[rloc * 4 + d];
    const int r  = r0 + rloc;
    const int n  = r % NN;
    const int bt = r / NN;
    const int t  = bt % NT;
    const int b  = bt / NT;
    if (t < NT - 1) {
      const int oidx = ((b * NN + n) * (NT - 1) + t) * ND + d;
      if (isbf) ((bf16_t*)outp)[oidx] = (bf16_t)a3;
      else      ((float*)outp)[oidx]  = a3;
    }
  }
}

extern "C" void kernel_launch(void* const* d_in, const int* in_sizes, int n_in,
                              void* d_out, int out_size, void* d_ws, size_t ws_size,
                              hipStream_t stream) {
  char* ws = (char*)d_ws;
  bf16_t* cb = (bf16_t*)(ws + 16);
  float* aggbuf = (float*)(ws + AGG_BYTE_OFF);

  convert_kernel<<<dim3(256), dim3(256), 0, stream>>>(
      d_in[0], d_in[1], d_in[4], d_in[5], d_in[6], d_in[7],
      d_in[8], d_in[9], d_in[10], d_in[11], d_in[12], d_in[13], d_ws);

  edge_kernel<<<dim3(NB * NT * 2), dim3(256), 0, stream>>>(
      cb + C_INPUTS, cb + C_RELTYPE, cb + C_W1F, cb + C_W2F,
      cb + C_B2, aggbuf);

  node_kernel<<<dim3((NB * NT * NN) / 64), dim3(256), 0, stream>>>(
      cb + C_INPUTS, cb + C_OW1F, cb + C_OB1, cb + C_OW2F, cb + C_OB2,
      cb + C_OW3, cb + C_OB3, (const int*)d_ws, aggbuf, d_out);
}